// Round 7
// baseline (2406.680 us; speedup 1.0000x reference)
//
#include <hip/hip_runtime.h>
#include <stdint.h>

#define CB 256
#define HWN 4096

// RNE fp32 -> bf16-grid fp32 value (final output cast emulation)
static __device__ __forceinline__ float rbf(float x){
  unsigned int u = __builtin_bit_cast(unsigned int, x);
  u = (u + 0x7fffu + ((u >> 16) & 1u)) & 0xffff0000u;
  return __builtin_bit_cast(float, u);
}

// ---------------- prep: s2_32[n] = numpy-pairwise f32 sum of fl32(w[n][c]^2), RAW fp32 w.
// numpy pairwise (n=256): two 128-blocks; each: 8 accumulators r[k]=a[k];
// r[k]+=a[8t+k] t=1..15; combine ((r0+r1)+(r2+r3))+((r4+r5)+(r6+r7)); blk0+blk1.
// mul-then-add, NO fma (numpy is built without fp contraction).
__global__ void vq_prep(const float* __restrict__ wcb, float* __restrict__ s2_32){
  int n = blockIdx.x * 256 + threadIdx.x;     // grid 4 x 256 = 1024
  const float* row = wcb + (size_t)n * CB;
  float blk[2];
  #pragma unroll
  for (int b2 = 0; b2 < 2; ++b2){
    float r[8];
    #pragma unroll
    for (int k = 0; k < 8; ++k){ float x = row[b2*128 + k]; r[k] = __fmul_rn(x, x); }
    for (int t = 1; t < 16; ++t)
      #pragma unroll
      for (int k = 0; k < 8; ++k){
        float x = row[b2*128 + t*8 + k];
        r[k] = __fadd_rn(r[k], __fmul_rn(x, x));
      }
    blk[b2] = __fadd_rn(__fadd_rn(__fadd_rn(r[0],r[1]), __fadd_rn(r[2],r[3])),
                        __fadd_rn(__fadd_rn(r[4],r[5]), __fadd_rn(r[6],r[7])));
  }
  s2_32[n] = __fadd_rn(blk[0], blk[1]);
}

// ---------------- main: fp64-true dots -> f32 round; np-exact f32 norms; argmin; outputs
__global__ __launch_bounds__(256, 4)
void vq_main(const float* __restrict__ ze, const float* __restrict__ wcb,
             const float* __restrict__ s2g, float* __restrict__ out,
             float* __restrict__ partial)
{
  __shared__ float zs[32*257];   // raw f32 z tile [pos][chan], pad 1 (bank-clean)
  __shared__ float s2l[1024];
  __shared__ float s1l[32];
  __shared__ float mv[256];
  __shared__ int   mi[256];
  __shared__ int   sel[32];
  __shared__ float red[256];

  const int tid = threadIdx.x;
  const int bid = blockIdx.x;
  const int b   = bid >> 7;            // 2048 blocks: 16 batches x 128
  const int hw0 = (bid & 127) * 32;    // 32 positions per block
  const int p   = tid & 31;
  const int g   = tid >> 5;            // code-eighth: codes g*128 .. g*128+127

  // ---- stage raw z into LDS (coalesced)
  {
    const float* zb = ze + (size_t)b * CB * HWN + hw0;
    for (int k = 0; k < 32; ++k){
      int idx = k*256 + tid;           // 0..8191
      int c = idx >> 5, pp = idx & 31;
      zs[pp*257 + c] = zb[(size_t)c * HWN + pp];
    }
    for (int k = 0; k < 4; ++k) s2l[k*256 + tid] = s2g[k*256 + tid];
  }
  __syncthreads();

  // ---- s1[p]: numpy-pairwise f32 sum of fl32(z^2), bit-exact np structure
  if (tid < 32){
    float blk[2];
    #pragma unroll
    for (int b2 = 0; b2 < 2; ++b2){
      float r[8];
      #pragma unroll
      for (int k = 0; k < 8; ++k){ float x = zs[tid*257 + b2*128 + k]; r[k] = __fmul_rn(x, x); }
      for (int t = 1; t < 16; ++t)
        #pragma unroll
        for (int k = 0; k < 8; ++k){
          float x = zs[tid*257 + b2*128 + t*8 + k];
          r[k] = __fadd_rn(r[k], __fmul_rn(x, x));
        }
      blk[b2] = __fadd_rn(__fadd_rn(__fadd_rn(r[0],r[1]), __fadd_rn(r[2],r[3])),
                          __fadd_rn(__fadd_rn(r[4],r[5]), __fadd_rn(r[6],r[7])));
    }
    s1l[tid] = __fadd_rn(blk[0], blk[1]);
  }
  __syncthreads();

  // ---- per-thread: 128 codes, fp64-true dot, f32-rounded np dist, argmin
  const float s1p = s1l[p];
  float bmin = 3.4e38f;
  int   bidx = 0;

  for (int oct = 0; oct < 16; ++oct){
    const int nb = g*128 + oct*8;
    double acc[8] = {0,0,0,0,0,0,0,0};
    for (int ch = 0; ch < 4; ++ch){
      // 64 channels of z -> f64 regs (LDS reads conflict-free: (p+c)%32 distinct)
      double zd[64];
      #pragma unroll
      for (int cc = 0; cc < 64; ++cc)
        zd[cc] = (double)zs[p*257 + ch*64 + cc];
      #pragma unroll
      for (int j = 0; j < 8; ++j){
        const float* wr = wcb + (size_t)(nb + j) * CB + ch*64;
        #pragma unroll
        for (int cc = 0; cc < 64; ++cc)
          acc[j] = fma(zd[cc], (double)wr[cc], acc[j]);
      }
    }
    #pragma unroll
    for (int j = 0; j < 8; ++j){
      float e32 = (float)acc[j];                       // fl32(true dot)
      float T   = __fadd_rn(s1p, s2l[nb + j]);         // fl(s1+s2)
      float d   = __fsub_rn(T, __fmul_rn(2.0f, e32));  // fl(T - 2e)
      if (d < bmin){ bmin = d; bidx = nb + j; }        // strict <, ascending n
    }
  }

  mv[tid] = bmin; mi[tid] = bidx;
  __syncthreads();

  // merge eighths (ascending g, strict < keeps first index)
  if (tid < 32){
    float v = mv[tid]; int ix = mi[tid];
    #pragma unroll
    for (int g2 = 1; g2 < 8; ++g2){
      float ov = mv[g2*32 + tid];
      int   oi = mi[g2*32 + tid];
      if (ov < v){ v = ov; ix = oi; }
    }
    sel[tid] = ix;
  }
  __syncthreads();

  // ---- epilogue: STE in raw f32, final bf16 cast; loss in f32
  {
    const int cseg = tid >> 5;          // 32 channels per thread
    const int code = sel[p];
    const float* qrow = wcb + (size_t)code * CB;
    float* outb = out + (size_t)b * CB * HWN + hw0 + p;
    float lacc = 0.f;
    for (int k = 0; k < 32; ++k){
      int c = cseg*32 + k;
      float zq = qrow[c];                              // raw f32 codebook
      float zf = zs[p*257 + c];                        // raw f32 ze
      float st = __fadd_rn(zf, __fsub_rn(zq, zf));     // f32 STE: ze + (zq - ze)
      outb[(size_t)c * HWN] = rbf(st);                 // final bf16 cast
      float dd = __fsub_rn(zf, zq);
      lacc = __fadd_rn(lacc, __fmul_rn(dd, dd));
    }
    red[tid] = lacc;
  }
  __syncthreads();
  for (int s = 128; s > 0; s >>= 1){
    if (tid < s) red[tid] += red[tid + s];
    __syncthreads();
  }
  if (tid == 0) partial[bid] = red[0];
}

// ---------------- loss: vq[b] = fl(m + fl(0.25*m)), m = fl(sum/2^20); final bf16 cast
__global__ void vq_loss(const float* __restrict__ partial, float* __restrict__ outl){
  int t = threadIdx.x;
  if (t < 16){
    float s = 0.f;
    for (int j = 0; j < 128; ++j) s += partial[t*128 + j];
    float m = __fmul_rn(s, 1.0f / 1048576.0f);
    outl[t] = rbf(__fadd_rn(m, __fmul_rn(0.25f, m)));
  }
}

extern "C" void kernel_launch(void* const* d_in, const int* in_sizes, int n_in,
                              void* d_out, int out_size, void* d_ws, size_t ws_size,
                              hipStream_t stream)
{
  const float* ze  = (const float*)d_in[0];   // z_e  [16,256,64,64] RAW fp32
  const float* wcb = (const float*)d_in[1];   // embed_w [1024,256] RAW fp32
  float* out = (float*)d_out;                 // z_q_st (bf16-grid f32) + vq_loss[16]
  float* s2_32   = (float*)d_ws;              // [1024]
  float* partial = s2_32 + 1024;              // [2048]

  hipLaunchKernelGGL(vq_prep, dim3(4), dim3(256), 0, stream, wcb, s2_32);
  hipLaunchKernelGGL(vq_main, dim3(2048), dim3(256), 0, stream,
                     ze, wcb, s2_32, out, partial);
  hipLaunchKernelGGL(vq_loss, dim3(1), dim3(64), 0, stream,
                     partial, out + (size_t)16 * 256 * 4096);
}

// Round 8
// 323.651 us; speedup vs baseline: 7.4360x; 7.4360x over previous
//
#include <hip/hip_runtime.h>
#include <stdint.h>

typedef __attribute__((ext_vector_type(8))) short short8;
typedef __attribute__((ext_vector_type(4))) float f32x4;
typedef __attribute__((ext_vector_type(4))) unsigned int u32x4;

#define CB 256
#define HWN 4096
#define NB 64
#define NCHUNK 16
#define THR 0.5f
#define MAXC 16

// RNE fp32 -> bf16-grid fp32 (final output cast)
static __device__ __forceinline__ float rbf(float x){
  unsigned int u = __builtin_bit_cast(unsigned int, x);
  u = (u + 0x7fffu + ((u >> 16) & 1u)) & 0xffff0000u;
  return __builtin_bit_cast(float, u);
}
// RNE fp32 pair -> packed bf16x2
static __device__ __forceinline__ unsigned int pk2(float a, float b){
  unsigned int ua = __builtin_bit_cast(unsigned int, a);
  unsigned int ub = __builtin_bit_cast(unsigned int, b);
  ua = (ua + 0x7fffu + ((ua >> 16) & 1u)) >> 16;
  ub = (ub + 0x7fffu + ((ub >> 16) & 1u)) & 0xffff0000u;
  return ua | ub;
}

// ---------------- prep: s2[n] = np-pairwise f32 sum of w[n][c]^2 (RAW f32; r7-proven)
__global__ void vq_prep(const float* __restrict__ wcb, float* __restrict__ s2g){
  int n = blockIdx.x * 256 + threadIdx.x;
  const float* row = wcb + (size_t)n * CB;
  float blk[2];
  #pragma unroll
  for (int b2 = 0; b2 < 2; ++b2){
    float r[8];
    #pragma unroll
    for (int k = 0; k < 8; ++k){ float x = row[b2*128 + k]; r[k] = __fmul_rn(x, x); }
    for (int t = 1; t < 16; ++t)
      #pragma unroll
      for (int k = 0; k < 8; ++k){
        float x = row[b2*128 + t*8 + k];
        r[k] = __fadd_rn(r[k], __fmul_rn(x, x));
      }
    blk[b2] = __fadd_rn(__fadd_rn(__fadd_rn(r[0],r[1]), __fadd_rn(r[2],r[3])),
                        __fadd_rn(__fadd_rn(r[4],r[5]), __fadd_rn(r[6],r[7])));
  }
  s2g[n] = __fadd_rn(blk[0], blk[1]);
}

// ---------------- s1 kernel: s1[pos] = np-pairwise f32 sum of z[pos][c]^2
// grid 256 x 256; block = 256 consecutive positions of one batch; coalesced.
__global__ void vq_s1(const float* __restrict__ ze, float* __restrict__ s1g){
  int pos = blockIdx.x * 256 + threadIdx.x;
  int b = pos >> 12, hw = pos & 4095;
  const float* zp = ze + (size_t)b * CB * HWN + hw;
  float blk[2];
  #pragma unroll
  for (int b2 = 0; b2 < 2; ++b2){
    float r[8];
    for (int t = 0; t < 16; ++t)
      #pragma unroll
      for (int k = 0; k < 8; ++k){
        float x = zp[(size_t)(b2*128 + t*8 + k) * HWN];
        float q = __fmul_rn(x, x);
        if (t == 0) r[k] = q; else r[k] = __fadd_rn(r[k], q);
      }
    blk[b2] = __fadd_rn(__fadd_rn(__fadd_rn(r[0],r[1]), __fadd_rn(r[2],r[3])),
                        __fadd_rn(__fadd_rn(r[4],r[5]), __fadd_rn(r[6],r[7])));
  }
  s1g[pos] = __fadd_rn(blk[0], blk[1]);
}

// ---------------- main: MFMA screen (2 passes) + exact f64 re-rank + outputs
__global__ __launch_bounds__(256, 2)
void vq_main(const float* __restrict__ ze, const float* __restrict__ wcb,
             const float* __restrict__ s2g, const float* __restrict__ s1g,
             float* __restrict__ out, float* __restrict__ partial)
{
  __shared__ __align__(16) char smem[65536];  // [0,32K): zeT bf16 swz; [32K,64K): B chunk
  __shared__ float selv[128];
  __shared__ float minl[64];
  __shared__ int   cnt[64];
  __shared__ int   list[64][MAXC];
  __shared__ float dex[64][MAXC];
  __shared__ int   sel[64];
  __shared__ float red[256];

  const int tid = threadIdx.x;
  const int bid = blockIdx.x;
  const int b   = bid >> 6;
  const int hw0 = (bid & 63) * 64;
  const int wid  = tid >> 6;
  const int lane = tid & 63;
  const int l15  = lane & 15;
  const int lq   = lane >> 4;
  const int wr = wid >> 1, wc = wid & 1;

  // ---- phase A: raw f32 -> bf16 zeT[p][c] (RNE, granule-swizzled)
  {
    const int p  = tid & 63;
    const int cg = tid >> 6;
    const float* zp = ze + (size_t)b * CB * HWN + hw0 + p;
    #pragma unroll
    for (int o = 0; o < 8; ++o){
      int c0 = cg*64 + o*8;
      float v[8];
      #pragma unroll
      for (int i = 0; i < 8; ++i) v[i] = zp[(size_t)(c0 + i) * HWN];
      int g = (c0 >> 3) ^ (p & 7);
      u32x4 pk = { pk2(v[0],v[1]), pk2(v[2],v[3]), pk2(v[4],v[5]), pk2(v[6],v[7]) };
      *(u32x4*)(smem + p*512 + g*16) = pk;
    }
  }
  if (tid < 64) cnt[tid] = 0;
  __syncthreads();

  // per-lane row constants: np-exact s1 for the 8 output rows
  float szr[8];
  {
    int rowbase = wr*32 + lq*4;
    const float* s1b = s1g + (size_t)b * HWN + hw0;
    #pragma unroll
    for (int m = 0; m < 2; ++m)
      #pragma unroll
      for (int r = 0; r < 4; ++r)
        szr[m*4+r] = s1b[rowbase + m*16 + r];
  }

  const int rA0 = wr*32 + l15, rA1 = rA0 + 16;
  const int rB0 = wc*32 + l15, rB1 = rB0 + 16;

  // =================== PASS 1: per-position min of approx dist ===============
  float minv[8];
  #pragma unroll
  for (int i = 0; i < 8; ++i) minv[i] = 3.4e38f;

  for (int ch = 0; ch < NCHUNK; ++ch){
    const int n0 = ch * NB;
    #pragma unroll
    for (int j = 0; j < 8; ++j){
      int id = j*256 + tid;
      int r  = id >> 5, qp = id & 31, sg = qp ^ (r & 7);
      const float* src = wcb + (size_t)(n0 + r) * CB + sg*8;
      f32x4 va = *(const f32x4*)(src);
      f32x4 vb = *(const f32x4*)(src + 4);
      u32x4 pk = { pk2(va[0],va[1]), pk2(va[2],va[3]), pk2(vb[0],vb[1]), pk2(vb[2],vb[3]) };
      *(u32x4*)(smem + 32768 + r*512 + qp*16) = pk;
    }
    float sw0 = s2g[n0 + wc*32 + l15];
    float sw1 = s2g[n0 + wc*32 + 16 + l15];
    __syncthreads();

    f32x4 acc00 = {0,0,0,0}, acc01 = {0,0,0,0}, acc10 = {0,0,0,0}, acc11 = {0,0,0,0};
    #pragma unroll
    for (int ks = 0; ks < 8; ++ks){
      int gk = ks*4 + lq;
      short8 a0 = *(const short8*)(smem +          rA0*512 + ((gk ^ (rA0 & 7)) << 4));
      short8 a1 = *(const short8*)(smem +          rA1*512 + ((gk ^ (rA1 & 7)) << 4));
      short8 b0 = *(const short8*)(smem + 32768 +  rB0*512 + ((gk ^ (rB0 & 7)) << 4));
      short8 b1 = *(const short8*)(smem + 32768 +  rB1*512 + ((gk ^ (rB1 & 7)) << 4));
      acc00 = __builtin_amdgcn_mfma_f32_16x16x32_bf16(a0, b0, acc00, 0, 0, 0);
      acc01 = __builtin_amdgcn_mfma_f32_16x16x32_bf16(a0, b1, acc01, 0, 0, 0);
      acc10 = __builtin_amdgcn_mfma_f32_16x16x32_bf16(a1, b0, acc10, 0, 0, 0);
      acc11 = __builtin_amdgcn_mfma_f32_16x16x32_bf16(a1, b1, acc11, 0, 0, 0);
    }
    __syncthreads();

    #pragma unroll
    for (int m = 0; m < 2; ++m)
      #pragma unroll
      for (int r = 0; r < 4; ++r){
        float sz = szr[m*4+r];
        float e0 = (m == 0) ? acc00[r] : acc10[r];
        float d0 = __fsub_rn(__fadd_rn(sz, sw0), 2.0f*e0);
        if (d0 < minv[m*4+r]) minv[m*4+r] = d0;
        float e1 = (m == 0) ? acc01[r] : acc11[r];
        float d1 = __fsub_rn(__fadd_rn(sz, sw1), 2.0f*e1);
        if (d1 < minv[m*4+r]) minv[m*4+r] = d1;
      }
  }

  // cross-lane value-min within 16-lane groups
  #pragma unroll
  for (int i = 0; i < 8; ++i){
    float v = minv[i];
    #pragma unroll
    for (int off = 1; off < 16; off <<= 1)
      v = fminf(v, __shfl_xor(v, off, 64));
    minv[i] = v;
  }
  if (l15 == 0){
    #pragma unroll
    for (int m = 0; m < 2; ++m)
      #pragma unroll
      for (int r = 0; r < 4; ++r)
        selv[wc*64 + wr*32 + m*16 + lq*4 + r] = minv[m*4+r];
  }
  __syncthreads();
  if (tid < 64) minl[tid] = fminf(selv[tid], selv[64 + tid]);
  __syncthreads();

  // =================== PASS 2: collect candidates (d_a <= min + THR) =========
  for (int ch = 0; ch < NCHUNK; ++ch){
    const int n0 = ch * NB;
    #pragma unroll
    for (int j = 0; j < 8; ++j){
      int id = j*256 + tid;
      int r  = id >> 5, qp = id & 31, sg = qp ^ (r & 7);
      const float* src = wcb + (size_t)(n0 + r) * CB + sg*8;
      f32x4 va = *(const f32x4*)(src);
      f32x4 vb = *(const f32x4*)(src + 4);
      u32x4 pk = { pk2(va[0],va[1]), pk2(va[2],va[3]), pk2(vb[0],vb[1]), pk2(vb[2],vb[3]) };
      *(u32x4*)(smem + 32768 + r*512 + qp*16) = pk;
    }
    float sw0 = s2g[n0 + wc*32 + l15];
    float sw1 = s2g[n0 + wc*32 + 16 + l15];
    __syncthreads();

    f32x4 acc00 = {0,0,0,0}, acc01 = {0,0,0,0}, acc10 = {0,0,0,0}, acc11 = {0,0,0,0};
    #pragma unroll
    for (int ks = 0; ks < 8; ++ks){
      int gk = ks*4 + lq;
      short8 a0 = *(const short8*)(smem +          rA0*512 + ((gk ^ (rA0 & 7)) << 4));
      short8 a1 = *(const short8*)(smem +          rA1*512 + ((gk ^ (rA1 & 7)) << 4));
      short8 b0 = *(const short8*)(smem + 32768 +  rB0*512 + ((gk ^ (rB0 & 7)) << 4));
      short8 b1 = *(const short8*)(smem + 32768 +  rB1*512 + ((gk ^ (rB1 & 7)) << 4));
      acc00 = __builtin_amdgcn_mfma_f32_16x16x32_bf16(a0, b0, acc00, 0, 0, 0);
      acc01 = __builtin_amdgcn_mfma_f32_16x16x32_bf16(a0, b1, acc01, 0, 0, 0);
      acc10 = __builtin_amdgcn_mfma_f32_16x16x32_bf16(a1, b0, acc10, 0, 0, 0);
      acc11 = __builtin_amdgcn_mfma_f32_16x16x32_bf16(a1, b1, acc11, 0, 0, 0);
    }
    __syncthreads();

    #pragma unroll
    for (int m = 0; m < 2; ++m)
      #pragma unroll
      for (int r = 0; r < 4; ++r){
        int row = wr*32 + m*16 + lq*4 + r;
        float lim = minl[row] + THR;
        float sz = szr[m*4+r];
        float e0 = (m == 0) ? acc00[r] : acc10[r];
        float d0 = __fsub_rn(__fadd_rn(sz, sw0), 2.0f*e0);
        if (d0 <= lim){
          int s = atomicAdd(&cnt[row], 1);
          if (s < MAXC) list[row][s] = n0 + wc*32 + l15;
        }
        float e1 = (m == 0) ? acc01[r] : acc11[r];
        float d1 = __fsub_rn(__fadd_rn(sz, sw1), 2.0f*e1);
        if (d1 <= lim){
          int s = atomicAdd(&cnt[row], 1);
          if (s < MAXC) list[row][s] = n0 + wc*32 + 16 + l15;
        }
      }
  }
  __syncthreads();

  // =================== exact f64 re-rank of candidates (r7-proven math) ======
  {
    const int pos = tid & 63;
    const int c_ = min(cnt[pos], MAXC);
    const float* zr = ze + (size_t)b * CB * HWN + hw0 + pos;
    const float s1p = s1g[(size_t)b * HWN + hw0 + pos];
    for (int sb = 0; sb < MAXC; sb += 4){
      int slot = sb + (tid >> 6);
      if (slot < c_){
        int code = list[pos][slot];
        const float* wrow = wcb + (size_t)code * CB;
        double a = 0.0;
        #pragma unroll 8
        for (int c = 0; c < 256; ++c)
          a = fma((double)zr[(size_t)c * HWN], (double)wrow[c], a);
        float e32 = (float)a;
        float T = __fadd_rn(s1p, s2g[code]);
        dex[pos][slot] = __fsub_rn(T, __fmul_rn(2.0f, e32));
      }
    }
  }
  __syncthreads();

  if (tid < 64){
    int c_ = cnt[tid];
    float bv = 3.4e38f; int bi = 0x7fffffff;
    if (c_ <= MAXC){
      for (int s = 0; s < c_; ++s){
        float d = dex[tid][s]; int ix = list[tid][s];
        if (d < bv || (d == bv && ix < bi)){ bv = d; bi = ix; }
      }
    } else {
      // overflow fallback: full exact scan (correct; never expected)
      const float* zr = ze + (size_t)b * CB * HWN + hw0 + tid;
      const float s1p = s1g[(size_t)b * HWN + hw0 + tid];
      for (int n = 0; n < 1024; ++n){
        double a = 0.0;
        for (int c = 0; c < 256; ++c)
          a = fma((double)zr[(size_t)c * HWN], (double)wcb[(size_t)n * CB + c], a);
        float e32 = (float)a;
        float d = __fsub_rn(__fadd_rn(s1p, s2g[n]), __fmul_rn(2.0f, e32));
        if (d < bv){ bv = d; bi = n; }
      }
    }
    sel[tid] = bi;
  }
  __syncthreads();

  // =================== epilogue: STE output (f32 -> bf16 cast) + loss ========
  {
    const int p    = tid & 63;
    const int cseg = tid >> 6;       // 4 segments x 64 channels
    const int code = sel[p];
    const float* qrow = wcb + (size_t)code * CB;
    const float* zcol = ze  + (size_t)b * CB * HWN + hw0 + p;
    float*       outb = out + (size_t)b * CB * HWN + hw0 + p;
    float lacc = 0.f;
    for (int k = 0; k < 64; ++k){
      int c = cseg*64 + k;
      float zq = qrow[c];
      float zf = zcol[(size_t)c * HWN];
      float st = __fadd_rn(zf, __fsub_rn(zq, zf));   // f32 STE
      outb[(size_t)c * HWN] = rbf(st);               // final bf16 cast
      float dd = __fsub_rn(zf, zq);
      lacc = __fadd_rn(lacc, __fmul_rn(dd, dd));
    }
    red[tid] = lacc;
  }
  __syncthreads();
  for (int s = 128; s > 0; s >>= 1){
    if (tid < s) red[tid] += red[tid + s];
    __syncthreads();
  }
  if (tid == 0) partial[bid] = red[0];
}

// ---------------- loss: vq[b] = fl(m + fl(0.25*m)), m = fl(sum/2^20); bf16 cast
__global__ void vq_loss(const float* __restrict__ partial, float* __restrict__ outl){
  int t = threadIdx.x;
  if (t < 16){
    float s = 0.f;
    for (int j = 0; j < 64; ++j) s += partial[t*64 + j];
    float m = __fmul_rn(s, 1.0f / 1048576.0f);
    outl[t] = rbf(__fadd_rn(m, __fmul_rn(0.25f, m)));
  }
}

extern "C" void kernel_launch(void* const* d_in, const int* in_sizes, int n_in,
                              void* d_out, int out_size, void* d_ws, size_t ws_size,
                              hipStream_t stream)
{
  const float* ze  = (const float*)d_in[0];   // z_e  [16,256,64,64] raw f32
  const float* wcb = (const float*)d_in[1];   // embed_w [1024,256] raw f32
  float* out = (float*)d_out;                 // z_q_st (bf16-grid f32) + vq_loss[16]
  float* s2g     = (float*)d_ws;              // [1024]
  float* s1gbuf  = s2g + 1024;                // [65536]
  float* partial = s1gbuf + 65536;            // [1024]

  hipLaunchKernelGGL(vq_prep, dim3(4),    dim3(256), 0, stream, wcb, s2g);
  hipLaunchKernelGGL(vq_s1,   dim3(256),  dim3(256), 0, stream, ze, s1gbuf);
  hipLaunchKernelGGL(vq_main, dim3(1024), dim3(256), 0, stream,
                     ze, wcb, s2g, s1gbuf, out, partial);
  hipLaunchKernelGGL(vq_loss, dim3(1),    dim3(64), 0, stream,
                     partial, out + (size_t)16 * 256 * 4096);
}